// Round 1
// baseline (973.036 us; speedup 1.0000x reference)
//
#include <hip/hip_runtime.h>

#define NH    32
#define HS    128
#define NPT   2048
#define NSQ   4
#define GD    64
#define NT    2112
#define NBLK  1024
#define BS    16
#define MBMAX 32
#define LSEQ  512
#define SCALE 0.08838834764831845f
#define NEG_INF -1000000000.0f

// ---------------- winner map: last (max) token writing each cache slot ------
__global__ void init_winner(int* __restrict__ w) {
    int i = blockIdx.x * 256 + threadIdx.x;
    if (i < NBLK * BS) w[i] = -1;
}

__global__ void fill_winner(const int* __restrict__ sm, int* __restrict__ w) {
    int t = blockIdx.x * 256 + threadIdx.x;
    if (t < NT) atomicMax(&w[sm[t]], t);
}

// ---------------- prompt attention: flash-style, fp32, 64x64 tiles ---------
// grid: 1024 = NSQ(4) * NH(32) * 8 qtiles ; block: 256
__global__ __launch_bounds__(256, 1) void prompt_attn(
    const float* __restrict__ q, const float* __restrict__ k,
    const float* __restrict__ v, float* __restrict__ out) {

    __shared__ float Qs[64 * 132];   // row stride 132 (HS+4) -> float4-aligned, bank-spread
    __shared__ float Ks[64 * 132];
    __shared__ float Vs[64 * 132];
    __shared__ float Ss[64 * 65];    // scores / probs, stride 65
    __shared__ float arow[64];
    __shared__ float lrow[64];

    const int tid = threadIdx.x;
    const int qt  = 7 - (blockIdx.x & 7);          // heavy tiles dispatched first
    const int h   = (blockIdx.x >> 3) & 31;
    const int s   = blockIdx.x >> 8;

    const int qbase = s * LSEQ + qt * 64;          // first query token of tile
    const int kbase0 = s * LSEQ;

    // ---- load Q tile (coalesced float4) ----
    {
        const int r0 = tid >> 5;                   // 0..7
        const int c4 = (tid & 31) * 4;             // 0..124
        #pragma unroll
        for (int p = 0; p < 8; ++p) {
            int r = r0 + p * 8;
            const float4 t = *(const float4*)(q + (size_t)(qbase + r) * (NH * HS) + h * HS + c4);
            *(float4*)(Qs + r * 132 + c4) = t;
        }
    }

    // per-thread roles
    const int rb = tid >> 4, cb = tid & 15;            // score mapping: 4x4 reg block, stride-16
    const int sr = tid >> 2, sseg = (tid & 3) * 16;    // softmax: 4 threads per row
    const int pr0 = (tid >> 3) * 2, pr1 = pr0 + 1;     // PV: 2 rows per thread
    const int pd  = (tid & 7) * 4;                     // PV: d = pd + 32u

    float m_run = -__builtin_inff(), l_run = 0.f;      // valid for softmax role
    float4 o0[4], o1[4];
    #pragma unroll
    for (int u = 0; u < 4; ++u) {
        o0[u].x = o0[u].y = o0[u].z = o0[u].w = 0.f;
        o1[u].x = o1[u].y = o1[u].z = o1[u].w = 0.f;
    }

    for (int kt = 0; kt <= qt; ++kt) {
        // ---- load K tile ----
        {
            const int r0 = tid >> 5;
            const int c4 = (tid & 31) * 4;
            #pragma unroll
            for (int p = 0; p < 8; ++p) {
                int r = r0 + p * 8;
                const float4 t = *(const float4*)(k + (size_t)(kbase0 + kt * 64 + r) * (NH * HS) + h * HS + c4);
                *(float4*)(Ks + r * 132 + c4) = t;
            }
        }
        __syncthreads();

        // ---- scores: S = Q K^T  (each thread: rows rb+16i, cols cb+16j) ----
        float s4[4][4];
        #pragma unroll
        for (int i = 0; i < 4; ++i)
            #pragma unroll
            for (int j = 0; j < 4; ++j) s4[i][j] = 0.f;

        for (int d4 = 0; d4 < 32; ++d4) {
            float4 a[4], b[4];
            #pragma unroll
            for (int i = 0; i < 4; ++i) a[i] = *(const float4*)(Qs + (rb + 16 * i) * 132 + d4 * 4);
            #pragma unroll
            for (int j = 0; j < 4; ++j) b[j] = *(const float4*)(Ks + (cb + 16 * j) * 132 + d4 * 4);
            #pragma unroll
            for (int i = 0; i < 4; ++i)
                #pragma unroll
                for (int j = 0; j < 4; ++j)
                    s4[i][j] += a[i].x * b[j].x + a[i].y * b[j].y + a[i].z * b[j].z + a[i].w * b[j].w;
        }
        #pragma unroll
        for (int i = 0; i < 4; ++i) {
            #pragma unroll
            for (int j = 0; j < 4; ++j) {
                int r = rb + 16 * i, c = cb + 16 * j;
                float sv = s4[i][j] * SCALE;
                if (kt == qt && c > r) sv = NEG_INF;   // causal mask on diagonal tile
                Ss[r * 65 + c] = sv;
            }
        }
        __syncthreads();

        // ---- online softmax (4 threads per row) ----
        {
            float lm = -__builtin_inff();
            #pragma unroll
            for (int t = 0; t < 16; ++t) lm = fmaxf(lm, Ss[sr * 65 + sseg + t]);
            lm = fmaxf(lm, __shfl_xor(lm, 1));
            lm = fmaxf(lm, __shfl_xor(lm, 2));
            const float mnew  = fmaxf(m_run, lm);
            const float alpha = __expf(m_run - mnew);
            float lsum = 0.f;
            #pragma unroll
            for (int t = 0; t < 16; ++t) {
                float e = __expf(Ss[sr * 65 + sseg + t] - mnew);
                Ss[sr * 65 + sseg + t] = e;
                lsum += e;
            }
            lsum += __shfl_xor(lsum, 1);
            lsum += __shfl_xor(lsum, 2);
            l_run = l_run * alpha + lsum;
            m_run = mnew;
            if ((tid & 3) == 0) arow[sr] = alpha;
        }

        // ---- load V tile (overlaps softmax tail) ----
        {
            const int r0 = tid >> 5;
            const int c4 = (tid & 31) * 4;
            #pragma unroll
            for (int p = 0; p < 8; ++p) {
                int r = r0 + p * 8;
                const float4 t = *(const float4*)(v + (size_t)(kbase0 + kt * 64 + r) * (NH * HS) + h * HS + c4);
                *(float4*)(Vs + r * 132 + c4) = t;
            }
        }
        __syncthreads();

        // ---- PV accumulate: O = alpha*O + P V ----
        {
            const float a0 = arow[pr0], a1 = arow[pr1];
            #pragma unroll
            for (int u = 0; u < 4; ++u) {
                o0[u].x *= a0; o0[u].y *= a0; o0[u].z *= a0; o0[u].w *= a0;
                o1[u].x *= a1; o1[u].y *= a1; o1[u].z *= a1; o1[u].w *= a1;
            }
            for (int cc = 0; cc < 64; ++cc) {
                const float p0 = Ss[pr0 * 65 + cc];
                const float p1 = Ss[pr1 * 65 + cc];
                #pragma unroll
                for (int u = 0; u < 4; ++u) {
                    const float4 vv = *(const float4*)(Vs + cc * 132 + pd + 32 * u);
                    o0[u].x += p0 * vv.x; o0[u].y += p0 * vv.y; o0[u].z += p0 * vv.z; o0[u].w += p0 * vv.w;
                    o1[u].x += p1 * vv.x; o1[u].y += p1 * vv.y; o1[u].z += p1 * vv.z; o1[u].w += p1 * vv.w;
                }
            }
        }
        // no barrier needed here: next iteration's post-loadK barrier orders all hazards
    }

    if ((tid & 3) == 0) lrow[sr] = l_run;
    __syncthreads();
    {
        const float inv0 = 1.f / lrow[pr0];
        const float inv1 = 1.f / lrow[pr1];
        float* ob0 = out + (size_t)(qbase + pr0) * (NH * HS) + h * HS + pd;
        float* ob1 = out + (size_t)(qbase + pr1) * (NH * HS) + h * HS + pd;
        #pragma unroll
        for (int u = 0; u < 4; ++u) {
            float4 t0, t1;
            t0.x = o0[u].x * inv0; t0.y = o0[u].y * inv0; t0.z = o0[u].z * inv0; t0.w = o0[u].w * inv0;
            t1.x = o1[u].x * inv1; t1.y = o1[u].y * inv1; t1.z = o1[u].z * inv1; t1.w = o1[u].w * inv1;
            *(float4*)(ob0 + 32 * u) = t0;
            *(float4*)(ob1 + 32 * u) = t1;
        }
    }
}

// ---------------- decode attention: 1 wave per (g,h), paged KV gather ------
// grid: 2048 = GD(64) * NH(32) ; block: 64
__global__ __launch_bounds__(64) void decode_attn(
    const float* __restrict__ q, const float* __restrict__ k, const float* __restrict__ v,
    const float* __restrict__ kcache, const float* __restrict__ vcache,
    const int* __restrict__ bt, const int* __restrict__ cl,
    const int* __restrict__ winner, float* __restrict__ out) {

    __shared__ float sc[512];
    __shared__ int   wsave[512];
    __shared__ float qs[128];
    __shared__ float tile[128 * 17];   // [d][off], stride 17 -> conflict-free column reads

    const int lane = threadIdx.x;
    const int g = blockIdx.x >> 5;
    const int h = blockIdx.x & 31;
    const int n  = cl[g];
    const int nb = (n + 15) >> 4;

    {   // load q row into LDS
        const float2 t = *(const float2*)(q + (size_t)(NPT + g) * (NH * HS) + h * HS + lane * 2);
        qs[lane * 2]     = t.x;
        qs[lane * 2 + 1] = t.y;
    }
    __syncthreads();

    const int c = lane >> 4, off = lane & 15;

    // ---- phase 1: scores ----
    for (int jb = 0; jb < nb; ++jb) {
        const int blk = bt[g * MBMAX + jb];
        const int wt  = winner[blk * BS + off];
        if (c == 0) wsave[jb * 16 + off] = wt;
        const float* kb = kcache + ((size_t)blk * NH + h) * (HS * BS);
        __syncthreads();                    // tile reuse hazard vs previous iter
        #pragma unroll
        for (int i = 0; i < 8; ++i) {       // stage 128x16 K tile, coalesced 16B/lane
            const int e = lane * 4 + i * 256;
            const float4 t = *(const float4*)(kb + e);
            const int d = e >> 4, of = e & 15;
            float* p = tile + d * 17 + of;
            p[0] = t.x; p[1] = t.y; p[2] = t.z; p[3] = t.w;
        }
        // wave-uniform overrides for slots overwritten by fresh k
        for (int o2 = 0; o2 < 16; ++o2) {
            const int wt2 = __shfl(wt, o2);
            if (wt2 >= 0) {
                const float* kr = k + (size_t)wt2 * (NH * HS) + h * HS;
                tile[lane * 17 + o2]        = kr[lane];
                tile[(lane + 64) * 17 + o2] = kr[lane + 64];
            }
        }
        __syncthreads();
        float partial = 0.f;
        #pragma unroll
        for (int i = 0; i < 32; ++i) {
            const int d = i * 4 + c;
            partial += qs[d] * tile[d * 17 + off];
        }
        partial += __shfl_xor(partial, 16);
        partial += __shfl_xor(partial, 32);
        float sv = partial * SCALE;
        const int j = jb * 16 + off;
        if (j >= n) sv = NEG_INF;
        if (c == 0) sc[j] = sv;
    }
    __syncthreads();

    // ---- phase 2: softmax over nb*16 entries ----
    float m = -__builtin_inff();
    for (int j = lane; j < nb * 16; j += 64) m = fmaxf(m, sc[j]);
    #pragma unroll
    for (int d = 32; d; d >>= 1) m = fmaxf(m, __shfl_xor(m, d));
    float l = 0.f;
    for (int j = lane; j < nb * 16; j += 64) {
        const float e = __expf(sc[j] - m);
        sc[j] = e;
        l += e;
    }
    #pragma unroll
    for (int d = 32; d; d >>= 1) l += __shfl_xor(l, d);
    __syncthreads();

    // ---- phase 3: PV ----
    float acc0 = 0.f, acc1 = 0.f;
    for (int jb = 0; jb < nb; ++jb) {
        const int blk = bt[g * MBMAX + jb];
        const float* vb = vcache + ((size_t)blk * NH + h) * (HS * BS);
        __syncthreads();
        #pragma unroll
        for (int i = 0; i < 8; ++i) {
            const int e = lane * 4 + i * 256;
            const float4 t = *(const float4*)(vb + e);
            const int d = e >> 4, of = e & 15;
            float* p = tile + d * 17 + of;
            p[0] = t.x; p[1] = t.y; p[2] = t.z; p[3] = t.w;
        }
        for (int o2 = 0; o2 < 16; ++o2) {
            const int wt2 = wsave[jb * 16 + o2];
            if (wt2 >= 0) {
                const float* vr = v + (size_t)wt2 * (NH * HS) + h * HS;
                tile[lane * 17 + o2]        = vr[lane];
                tile[(lane + 64) * 17 + o2] = vr[lane + 64];
            }
        }
        __syncthreads();
        #pragma unroll
        for (int o2 = 0; o2 < 16; ++o2) {
            const float p = sc[jb * 16 + o2];
            acc0 += p * tile[lane * 17 + o2];
            acc1 += p * tile[(lane + 64) * 17 + o2];
        }
    }
    const float inv = 1.f / l;
    out[(size_t)(NPT + g) * (NH * HS) + h * HS + lane]      = acc0 * inv;
    out[(size_t)(NPT + g) * (NH * HS) + h * HS + lane + 64] = acc1 * inv;
}

extern "C" void kernel_launch(void* const* d_in, const int* in_sizes, int n_in,
                              void* d_out, int out_size, void* d_ws, size_t ws_size,
                              hipStream_t stream) {
    const float* q  = (const float*)d_in[0];
    const float* k  = (const float*)d_in[1];
    const float* v  = (const float*)d_in[2];
    const float* kc = (const float*)d_in[3];
    const float* vc = (const float*)d_in[4];
    const int* bt   = (const int*)d_in[5];
    const int* cl   = (const int*)d_in[6];
    const int* sm   = (const int*)d_in[7];
    float* out  = (float*)d_out;
    int* winner = (int*)d_ws;   // 16384 ints

    hipLaunchKernelGGL(init_winner, dim3(64),   dim3(256), 0, stream, winner);
    hipLaunchKernelGGL(fill_winner, dim3(9),    dim3(256), 0, stream, sm, winner);
    hipLaunchKernelGGL(prompt_attn, dim3(1024), dim3(256), 0, stream, q, k, v, out);
    hipLaunchKernelGGL(decode_attn, dim3(2048), dim3(64),  0, stream,
                       q, k, v, kc, vc, bt, cl, winner, out);
}

// Round 3
// 756.911 us; speedup vs baseline: 1.2855x; 1.2855x over previous
//
#include <hip/hip_runtime.h>
#include <stdint.h>

#define NH    32
#define HS    128
#define NPT   2048
#define NT    2112
#define NBLK  1024
#define BS    16
#define MBMAX 32
#define LSEQ  512
#define DMODEL 4096
#define SCALE 0.08838834764831845f

typedef __bf16 bf16x8 __attribute__((ext_vector_type(8)));
typedef float  f32x4  __attribute__((ext_vector_type(4)));

__device__ __forceinline__ unsigned short f2bf(float f) {
    unsigned u = __float_as_uint(f);
    u += 0x7fffu + ((u >> 16) & 1u);          // RNE
    return (unsigned short)(u >> 16);
}
__device__ __forceinline__ unsigned pack2(float a, float b) {
    return (unsigned)f2bf(a) | ((unsigned)f2bf(b) << 16);
}
__device__ __forceinline__ float sel4(const float a[4], int i) {
    float r = a[0];
    r = (i == 1) ? a[1] : r;
    r = (i == 2) ? a[2] : r;
    r = (i == 3) ? a[3] : r;
    return r;
}

// ---------------- winner map: last (max) token writing each cache slot ------
__global__ void init_winner(int* __restrict__ w) {
    int i = blockIdx.x * 256 + threadIdx.x;
    if (i < NBLK * BS) w[i] = -1;
}
__global__ void fill_winner(const int* __restrict__ sm, int* __restrict__ w) {
    int t = blockIdx.x * 256 + threadIdx.x;
    if (t < NT) atomicMax(&w[sm[t]], t);
}

// ---------------- prompt attention: bf16 MFMA flash, 64x64 tiles -----------
// grid 1024 = NSQ*NH*8 qtiles ; block 256 = 4 waves, wave owns 16 q-rows
#define QKS 136                     // Q/K LDS row stride (bf16), 16B aligned
// V^T row stride 72, XOR token swizzle (bits>=3 only -> no cross-row overlap,
// 4-token writes and 8-token reads stay contiguous)
__device__ __forceinline__ int vtidx(int d, int t) {
    return d * 72 + (t ^ (((d >> 3) & 3) * 8));
}

__global__ __launch_bounds__(256, 2) void prompt_attn(
    const float* __restrict__ q, const float* __restrict__ k,
    const float* __restrict__ v, float* __restrict__ out) {

    __shared__ __align__(16) unsigned short Qs[64 * QKS];
    __shared__ __align__(16) unsigned short Ks[64 * QKS];
    __shared__ __align__(16) unsigned short Vt[128 * 72 + 32];
    __shared__ __align__(16) unsigned short Ps[4 * 16 * 72];

    const int tid  = threadIdx.x;
    const int lane = tid & 63, wq = tid >> 6;
    const int quad = lane >> 4, m15 = lane & 15;
    const int qt = 7 - (blockIdx.x & 7);       // heavy tiles first
    const int h  = (blockIdx.x >> 3) & 31;
    const int s  = blockIdx.x >> 8;
    const int qbase  = s * LSEQ + qt * 64;
    const int kbase0 = s * LSEQ;

    // ---- stage Q (pre-scaled) as bf16 ----
    {
        const int r0 = tid >> 5, c4 = (tid & 31) * 4;
        #pragma unroll
        for (int p = 0; p < 8; ++p) {
            int r = r0 + p * 8;
            float4 t = *(const float4*)(q + (size_t)(qbase + r) * DMODEL + h * HS + c4);
            uint2 w; w.x = pack2(t.x * SCALE, t.y * SCALE); w.y = pack2(t.z * SCALE, t.w * SCALE);
            *(uint2*)(&Qs[r * QKS + c4]) = w;
        }
    }

    f32x4 O[8];
    #pragma unroll
    for (int i = 0; i < 8; ++i) O[i] = (f32x4){0.f, 0.f, 0.f, 0.f};
    float mrun[4], lrun[4];
    #pragma unroll
    for (int r = 0; r < 4; ++r) { mrun[r] = -1e30f; lrun[r] = 0.f; }

    unsigned short* Pw = Ps + wq * (16 * 72);

    for (int kt = 0; kt <= qt; ++kt) {
        // ---- stage K tile (bf16) ----
        {
            const int r0 = tid >> 5, c4 = (tid & 31) * 4;
            #pragma unroll
            for (int p = 0; p < 8; ++p) {
                int r = r0 + p * 8;
                float4 t = *(const float4*)(k + (size_t)(kbase0 + kt * 64 + r) * DMODEL + h * HS + c4);
                uint2 w; w.x = pack2(t.x, t.y); w.y = pack2(t.z, t.w);
                *(uint2*)(&Ks[r * QKS + c4]) = w;
            }
        }
        // ---- stage V^T (bf16) via in-register 4x4 shfl transpose ----
        {
            const int g = tid >> 2, sub = tid & 3;
            const int lbase = lane & ~3;
            #pragma unroll
            for (int p = 0; p < 8; ++p) {
                const int tb = (p & 3) * 16, db = (p >> 2) * 64;
                const int tok  = tb + (g >> 4) * 4 + sub;
                const int dim4 = db + (g & 15) * 4;
                float4 t = *(const float4*)(v + (size_t)(kbase0 + kt * 64 + tok) * DMODEL + h * HS + dim4);
                float in[4] = {t.x, t.y, t.z, t.w};
                float rec[4];
                #pragma unroll
                for (int r = 0; r < 4; ++r) {
                    float pub = sel4(in, (sub + 4 - r) & 3);
                    rec[r] = __shfl(pub, lbase + ((sub + r) & 3));
                }
                float o4[4];
                #pragma unroll
                for (int j = 0; j < 4; ++j) o4[j] = sel4(rec, (j + 4 - sub) & 3);
                const int d  = dim4 + sub;
                const int t0 = tb + (g >> 4) * 4;
                uint2 w2; w2.x = pack2(o4[0], o4[1]); w2.y = pack2(o4[2], o4[3]);
                *(uint2*)(&Vt[vtidx(d, t0)]) = w2;
            }
        }
        __syncthreads();

        // ---- QK^T: S[16 x 64] per wave via 16 MFMA ----
        bf16x8 aq[4];
        #pragma unroll
        for (int kc = 0; kc < 4; ++kc)
            aq[kc] = *(const bf16x8*)(&Qs[(wq * 16 + m15) * QKS + kc * 32 + quad * 8]);
        f32x4 S[4];
        #pragma unroll
        for (int nt = 0; nt < 4; ++nt) {
            S[nt] = (f32x4){0.f, 0.f, 0.f, 0.f};
            #pragma unroll
            for (int kc = 0; kc < 4; ++kc) {
                bf16x8 bk = *(const bf16x8*)(&Ks[(nt * 16 + m15) * QKS + kc * 32 + quad * 8]);
                S[nt] = __builtin_amdgcn_mfma_f32_16x16x32_bf16(aq[kc], bk, S[nt], 0, 0, 0);
            }
        }
        // causal mask on diagonal tile (C layout: row = quad*4+reg, col = nt*16+m15)
        if (kt == qt) {
            #pragma unroll
            for (int nt = 0; nt < 4; ++nt) {
                const int C = nt * 16 + m15;
                #pragma unroll
                for (int reg = 0; reg < 4; ++reg) {
                    const int R = wq * 16 + quad * 4 + reg;
                    if (C > R) S[nt][reg] = -1e30f;
                }
            }
        }

        // ---- online softmax per row (row lives in 16 lanes sharing quad) ----
        #pragma unroll
        for (int reg = 0; reg < 4; ++reg) {
            float x = fmaxf(fmaxf(S[0][reg], S[1][reg]), fmaxf(S[2][reg], S[3][reg]));
            x = fmaxf(x, __shfl_xor(x, 1));
            x = fmaxf(x, __shfl_xor(x, 2));
            x = fmaxf(x, __shfl_xor(x, 4));
            x = fmaxf(x, __shfl_xor(x, 8));
            const float mn = fmaxf(mrun[reg], x);
            const float al = __expf(mrun[reg] - mn);
            mrun[reg] = mn;
            float sum = 0.f;
            #pragma unroll
            for (int nt = 0; nt < 4; ++nt) {
                float pv = __expf(S[nt][reg] - mn);
                S[nt][reg] = pv;
                sum += pv;
            }
            sum += __shfl_xor(sum, 1);
            sum += __shfl_xor(sum, 2);
            sum += __shfl_xor(sum, 4);
            sum += __shfl_xor(sum, 8);
            lrun[reg] = lrun[reg] * al + sum;
            #pragma unroll
            for (int n2 = 0; n2 < 8; ++n2) O[n2][reg] *= al;
        }

        // ---- write P (bf16) to wave-private LDS, C layout -> row-major ----
        #pragma unroll
        for (int nt = 0; nt < 4; ++nt) {
            #pragma unroll
            for (int reg = 0; reg < 4; ++reg) {
                float v0 = S[nt][reg];
                float v1 = __shfl_xor(v0, 1);
                if (!(lane & 1))
                    *(unsigned*)(&Pw[(quad * 4 + reg) * 72 + nt * 16 + m15]) = pack2(v0, v1);
            }
        }

        // ---- PV: O[16 x 128] += P[16 x 64] * V[64 x 128] via 16 MFMA ----
        bf16x8 ap[2];
        #pragma unroll
        for (int kc = 0; kc < 2; ++kc)
            ap[kc] = *(const bf16x8*)(&Pw[m15 * 72 + kc * 32 + quad * 8]);
        #pragma unroll
        for (int n2 = 0; n2 < 8; ++n2) {
            #pragma unroll
            for (int kc = 0; kc < 2; ++kc) {
                bf16x8 bv = *(const bf16x8*)(&Vt[vtidx(n2 * 16 + m15, kc * 32 + quad * 8)]);
                O[n2] = __builtin_amdgcn_mfma_f32_16x16x32_bf16(ap[kc], bv, O[n2], 0, 0, 0);
            }
        }
        __syncthreads();   // protect Ks/Vt before next staging
    }

    // ---- epilogue: divide by l, store fp32 ----
    float inv[4];
    #pragma unroll
    for (int reg = 0; reg < 4; ++reg) inv[reg] = 1.f / lrun[reg];
    #pragma unroll
    for (int n2 = 0; n2 < 8; ++n2) {
        #pragma unroll
        for (int reg = 0; reg < 4; ++reg) {
            out[(size_t)(qbase + wq * 16 + quad * 4 + reg) * DMODEL + h * HS + n2 * 16 + m15] =
                O[n2][reg] * inv[reg];
        }
    }
}

// ---------------- decode: 4-wave split-context flash-decoding --------------
// grid 2048 = GD*NH ; block 256 ; wave w handles KV-blocks w, w+4, ...
__global__ __launch_bounds__(256, 4) void decode_attn(
    const float* __restrict__ q, const float* __restrict__ k, const float* __restrict__ v,
    const float* __restrict__ kcache, const float* __restrict__ vcache,
    const int* __restrict__ bt, const int* __restrict__ cl,
    const int* __restrict__ winner, float* __restrict__ out) {

    __shared__ float qs[128];
    __shared__ float tile[4][128 * 17];    // per-wave [d][off], stride 17
    __shared__ float pm[4], pl[4];
    __shared__ float pacc[4][128];

    const int tid = threadIdx.x, w = tid >> 6, lane = tid & 63;
    const int g = blockIdx.x >> 5, h = blockIdx.x & 31;
    const int n  = cl[g];
    const int nb = (n + 15) >> 4;

    if (tid < 64) {
        const float2 t = *(const float2*)(q + (size_t)(NPT + g) * DMODEL + h * HS + tid * 2);
        qs[tid * 2] = t.x; qs[tid * 2 + 1] = t.y;
    }
    __syncthreads();

    const int c = lane >> 4, off = lane & 15;
    float qreg[32];
    #pragma unroll
    for (int i = 0; i < 32; ++i) qreg[i] = qs[i * 4 + c];

    float m = -1e30f, l = 0.f, a0 = 0.f, a1 = 0.f;
    float* T = tile[w];

    for (int jb = w; jb < nb; jb += 4) {
        const int blk = bt[g * MBMAX + jb];
        const int wt  = winner[blk * BS + off];
        const float* kb = kcache + ((size_t)blk * NH + h) * (HS * BS);

        // stage K tile (coalesced 16B/lane), then wave-uniform fresh-k overrides
        #pragma unroll
        for (int i = 0; i < 8; ++i) {
            const int e = lane * 4 + i * 256;
            const float4 t = *(const float4*)(kb + e);
            const int d = e >> 4, of = e & 15;
            float* p = T + d * 17 + of;
            p[0] = t.x; p[1] = t.y; p[2] = t.z; p[3] = t.w;
        }
        #pragma unroll
        for (int o2 = 0; o2 < 16; ++o2) {
            const int wt2 = __shfl(wt, o2);
            if (wt2 >= 0) {
                const float* kr = k + (size_t)wt2 * DMODEL + h * HS;
                T[lane * 17 + o2]        = kr[lane];
                T[(lane + 64) * 17 + o2] = kr[lane + 64];
            }
        }
        // scores (LDS ops are in-order per wave; no barrier needed)
        float partial = 0.f;
        #pragma unroll
        for (int i = 0; i < 32; ++i) partial += qreg[i] * T[(i * 4 + c) * 17 + off];
        partial += __shfl_xor(partial, 16);
        partial += __shfl_xor(partial, 32);
        float sv = partial * SCALE;
        if (jb * 16 + off >= n) sv = -1e30f;

        // online softmax update (per wave)
        float tm = sv;
        tm = fmaxf(tm, __shfl_xor(tm, 1));
        tm = fmaxf(tm, __shfl_xor(tm, 2));
        tm = fmaxf(tm, __shfl_xor(tm, 4));
        tm = fmaxf(tm, __shfl_xor(tm, 8));
        const float mn = fmaxf(m, tm);
        const float al = __expf(m - mn);
        const float p  = __expf(sv - mn);
        float ps = p;
        ps += __shfl_xor(ps, 1);
        ps += __shfl_xor(ps, 2);
        ps += __shfl_xor(ps, 4);
        ps += __shfl_xor(ps, 8);
        l = l * al + ps;
        m = mn;
        a0 *= al; a1 *= al;

        // stage V tile + overrides (reuses T; wave-internal ordering is safe)
        const float* vb = vcache + ((size_t)blk * NH + h) * (HS * BS);
        #pragma unroll
        for (int i = 0; i < 8; ++i) {
            const int e = lane * 4 + i * 256;
            const float4 t = *(const float4*)(vb + e);
            const int d = e >> 4, of = e & 15;
            float* pp = T + d * 17 + of;
            pp[0] = t.x; pp[1] = t.y; pp[2] = t.z; pp[3] = t.w;
        }
        #pragma unroll
        for (int o2 = 0; o2 < 16; ++o2) {
            const int wt2 = __shfl(wt, o2);
            if (wt2 >= 0) {
                const float* vr = v + (size_t)wt2 * DMODEL + h * HS;
                T[lane * 17 + o2]        = vr[lane];
                T[(lane + 64) * 17 + o2] = vr[lane + 64];
            }
        }
        #pragma unroll
        for (int o2 = 0; o2 < 16; ++o2) {
            const float pp = __shfl(p, o2);
            a0 += pp * T[lane * 17 + o2];
            a1 += pp * T[(lane + 64) * 17 + o2];
        }
    }

    // cross-wave combine
    if (lane == 0) { pm[w] = m; pl[w] = l; }
    pacc[w][lane]      = a0;
    pacc[w][lane + 64] = a1;
    __syncthreads();
    if (tid < 128) {
        const float M = fmaxf(fmaxf(pm[0], pm[1]), fmaxf(pm[2], pm[3]));
        float L = 0.f, A = 0.f;
        #pragma unroll
        for (int w2 = 0; w2 < 4; ++w2) {
            const float e = __expf(pm[w2] - M);
            L += e * pl[w2];
            A += e * pacc[w2][tid];
        }
        out[(size_t)(NPT + g) * DMODEL + h * HS + tid] = A / L;
    }
}

extern "C" void kernel_launch(void* const* d_in, const int* in_sizes, int n_in,
                              void* d_out, int out_size, void* d_ws, size_t ws_size,
                              hipStream_t stream) {
    const float* q  = (const float*)d_in[0];
    const float* k  = (const float*)d_in[1];
    const float* v  = (const float*)d_in[2];
    const float* kc = (const float*)d_in[3];
    const float* vc = (const float*)d_in[4];
    const int* bt   = (const int*)d_in[5];
    const int* cl   = (const int*)d_in[6];
    const int* sm   = (const int*)d_in[7];
    float* out  = (float*)d_out;
    int* winner = (int*)d_ws;   // 16384 ints

    hipLaunchKernelGGL(init_winner, dim3(64),   dim3(256), 0, stream, winner);
    hipLaunchKernelGGL(fill_winner, dim3(9),    dim3(256), 0, stream, sm, winner);
    hipLaunchKernelGGL(prompt_attn, dim3(1024), dim3(256), 0, stream, q, k, v, out);
    hipLaunchKernelGGL(decode_attn, dim3(2048), dim3(256), 0, stream,
                       q, k, v, kc, vc, bt, cl, winner, out);
}